// Round 1
// baseline (425.287 us; speedup 1.0000x reference)
//
#include <hip/hip_runtime.h>
#include <math.h>

#define NN   50000
#define NE   800000
#define FIN  128
#define HID  256     // H1*C1
#define NH1  8
#define C2   128
#define CAP  64
#define NEGS 0.2f

// ---------------- CSR build: bucket scatter by destination ----------------
__global__ __launch_bounds__(256) void k_scatter(const int* __restrict__ ei,
                                                 int* __restrict__ cursor,
                                                 int* __restrict__ csr) {
    int e = blockIdx.x * 256 + threadIdx.x;
    if (e >= NE) return;
    int s = ei[e];
    int d = ei[NE + e];
    int slot = atomicAdd(&cursor[d], 1);
    if (slot < CAP) csr[d * CAP + slot] = s;
}

// ---------------- Layer 1 GEMM: xh1 = x @ W1^T, fused att logits ----------
// block: 256 threads. 16 rows x 256 cols per block. thread = 4 rows x 4 cols.
__global__ __launch_bounds__(256) void k_gemm1(const float* __restrict__ x,
                                               const float* __restrict__ w,
                                               const float* __restrict__ atti,
                                               const float* __restrict__ attj,
                                               float* __restrict__ xh,
                                               float* __restrict__ ai,
                                               float* __restrict__ aj) {
    __shared__ float xs[32][17];    // [kk][row], +1 pad kills transpose-store conflicts
    __shared__ float ws[32][256];   // [kk][col] = W[col][k0+kk]
    const int t  = threadIdx.x;
    const int tc = t & 63;          // col group (4 cols each)
    const int tr = t >> 6;          // row group == wave id (4 rows each)
    const int row0 = blockIdx.x * 16;

    float acc[4][4];
#pragma unroll
    for (int r = 0; r < 4; ++r)
#pragma unroll
        for (int c = 0; c < 4; ++c) acc[r][c] = 0.f;

    for (int k0 = 0; k0 < FIN; k0 += 32) {
        __syncthreads();
#pragma unroll
        for (int r = 0; r < 2; ++r) {
            int id = t + r * 256;
            int rr = id >> 5, kk = id & 31;
            xs[kk][rr] = x[(size_t)(row0 + rr) * FIN + k0 + kk];
        }
        {
            const float4* wp = (const float4*)(w + (size_t)t * FIN + k0);
#pragma unroll
            for (int q = 0; q < 8; ++q) {
                float4 v = wp[q];
                ws[q * 4 + 0][t] = v.x;
                ws[q * 4 + 1][t] = v.y;
                ws[q * 4 + 2][t] = v.z;
                ws[q * 4 + 3][t] = v.w;
            }
        }
        __syncthreads();
#pragma unroll
        for (int kk = 0; kk < 32; ++kk) {
            const float4 wv = ((const float4*)(&ws[kk][0]))[tc];
            const float x0 = xs[kk][tr * 4 + 0];
            const float x1 = xs[kk][tr * 4 + 1];
            const float x2 = xs[kk][tr * 4 + 2];
            const float x3 = xs[kk][tr * 4 + 3];
            acc[0][0] += x0 * wv.x; acc[0][1] += x0 * wv.y; acc[0][2] += x0 * wv.z; acc[0][3] += x0 * wv.w;
            acc[1][0] += x1 * wv.x; acc[1][1] += x1 * wv.y; acc[1][2] += x1 * wv.z; acc[1][3] += x1 * wv.w;
            acc[2][0] += x2 * wv.x; acc[2][1] += x2 * wv.y; acc[2][2] += x2 * wv.z; acc[2][3] += x2 * wv.w;
            acc[3][0] += x3 * wv.x; acc[3][1] += x3 * wv.y; acc[3][2] += x3 * wv.z; acc[3][3] += x3 * wv.w;
        }
    }

    // epilogue: write xh, reduce attention logits per (row, head)
    const float4 ai4 = ((const float4*)atti)[tc];
    const float4 aj4 = ((const float4*)attj)[tc];
    const int h = tc >> 3;          // 8 lanes (32 cols) per head
#pragma unroll
    for (int r = 0; r < 4; ++r) {
        const int row = row0 + tr * 4 + r;
        float4 v = make_float4(acc[r][0], acc[r][1], acc[r][2], acc[r][3]);
        ((float4*)(xh + (size_t)row * HID))[tc] = v;
        float vi = v.x * ai4.x + v.y * ai4.y + v.z * ai4.z + v.w * ai4.w;
        float vj = v.x * aj4.x + v.y * aj4.y + v.z * aj4.z + v.w * aj4.w;
#pragma unroll
        for (int off = 4; off; off >>= 1) {
            vi += __shfl_xor(vi, off, 8);
            vj += __shfl_xor(vj, off, 8);
        }
        if ((tc & 7) == 0) {
            ai[row * NH1 + h] = vi;
            aj[row * NH1 + h] = vj;
        }
    }
}

// ---------------- Layer 1 aggregation: one wave per destination node ------
__global__ __launch_bounds__(256) void k_agg1(const float* __restrict__ xh,
                                              const float* __restrict__ ai,
                                              const float* __restrict__ aj,
                                              const int* __restrict__ cursor,
                                              const int* __restrict__ csr,
                                              const float* __restrict__ bias,
                                              float* __restrict__ hout) {
    const int lane = threadIdx.x & 63;
    const int i    = blockIdx.x * 4 + (threadIdx.x >> 6);
    const int myh  = lane & 7;             // head this lane computes weights for
    const int hsel = lane >> 5;            // head of col j=0 is hsel, j adds 2
    const float a_i = ai[i * NH1 + myh];

    float acc0 = 0.f, acc1 = 0.f, acc2 = 0.f, acc3 = 0.f, dsum = 0.f;
    const int deg = min(cursor[i], CAP);
    const int* rowp = csr + (size_t)i * CAP;

    for (int e = 0; e <= deg; ++e) {       // last iteration: self loop
        const int s = (e == deg) ? i : rowp[e];
        float aw = a_i + aj[s * NH1 + myh];
        aw = aw > 0.f ? aw : NEGS * aw;
        const float wv = __expf(aw);       // no max-subtraction: shift-invariant
        dsum += wv;
        const float* xr = xh + (size_t)s * HID;
        acc0 += __shfl(wv, hsel + 0, 64) * xr[lane];
        acc1 += __shfl(wv, hsel + 2, 64) * xr[lane + 64];
        acc2 += __shfl(wv, hsel + 4, 64) * xr[lane + 128];
        acc3 += __shfl(wv, hsel + 6, 64) * xr[lane + 192];
    }
    const float d0 = __shfl(dsum, hsel + 0, 64);
    const float d1 = __shfl(dsum, hsel + 2, 64);
    const float d2 = __shfl(dsum, hsel + 4, 64);
    const float d3 = __shfl(dsum, hsel + 6, 64);
    float o0 = acc0 / (d0 + 1e-16f) + bias[lane];
    float o1 = acc1 / (d1 + 1e-16f) + bias[lane + 64];
    float o2 = acc2 / (d2 + 1e-16f) + bias[lane + 128];
    float o3 = acc3 / (d3 + 1e-16f) + bias[lane + 192];
    o0 = o0 > 0.f ? o0 : expm1f(o0);       // ELU
    o1 = o1 > 0.f ? o1 : expm1f(o1);
    o2 = o2 > 0.f ? o2 : expm1f(o2);
    o3 = o3 > 0.f ? o3 : expm1f(o3);
    float* hr = hout + (size_t)i * HID;
    hr[lane] = o0; hr[lane + 64] = o1; hr[lane + 128] = o2; hr[lane + 192] = o3;
}

// ---------------- Layer 2 GEMM: xh2 = h @ W2^T ----------------------------
// block: 256 threads. 16 rows x 128 cols. thread = 2 rows x 4 cols.
__global__ __launch_bounds__(256) void k_gemm2(const float* __restrict__ hin,
                                               const float* __restrict__ w,
                                               float* __restrict__ xh2) {
    __shared__ float hs[32][17];
    __shared__ float ws[32][128];
    const int t  = threadIdx.x;
    const int tc = t & 31;    // col group (4 cols)
    const int tr = t >> 5;    // row group (2 rows), half-wave uniform
    const int row0 = blockIdx.x * 16;

    float acc[2][4];
#pragma unroll
    for (int r = 0; r < 2; ++r)
#pragma unroll
        for (int c = 0; c < 4; ++c) acc[r][c] = 0.f;

    for (int k0 = 0; k0 < HID; k0 += 32) {
        __syncthreads();
#pragma unroll
        for (int r = 0; r < 2; ++r) {
            int id = t + r * 256;
            int rr = id >> 5, kk = id & 31;
            hs[kk][rr] = hin[(size_t)(row0 + rr) * HID + k0 + kk];
        }
        {
            const int c = t & 127;
            const int half = t >> 7;
            const float4* wp = (const float4*)(w + (size_t)c * HID + k0 + half * 16);
#pragma unroll
            for (int q = 0; q < 4; ++q) {
                float4 v = wp[q];
                ws[half * 16 + q * 4 + 0][c] = v.x;
                ws[half * 16 + q * 4 + 1][c] = v.y;
                ws[half * 16 + q * 4 + 2][c] = v.z;
                ws[half * 16 + q * 4 + 3][c] = v.w;
            }
        }
        __syncthreads();
#pragma unroll
        for (int kk = 0; kk < 32; ++kk) {
            const float4 wv = ((const float4*)(&ws[kk][0]))[tc];
            const float h0 = hs[kk][tr * 2 + 0];
            const float h1 = hs[kk][tr * 2 + 1];
            acc[0][0] += h0 * wv.x; acc[0][1] += h0 * wv.y; acc[0][2] += h0 * wv.z; acc[0][3] += h0 * wv.w;
            acc[1][0] += h1 * wv.x; acc[1][1] += h1 * wv.y; acc[1][2] += h1 * wv.z; acc[1][3] += h1 * wv.w;
        }
    }
#pragma unroll
    for (int r = 0; r < 2; ++r) {
        const int row = row0 + tr * 2 + r;
        ((float4*)(xh2 + (size_t)row * C2))[tc] =
            make_float4(acc[r][0], acc[r][1], acc[r][2], acc[r][3]);
    }
}

// ---------------- Layer 2 attention logits --------------------------------
__global__ __launch_bounds__(256) void k_att2(const float* __restrict__ xh2,
                                              const float* __restrict__ atti,
                                              const float* __restrict__ attj,
                                              float* __restrict__ ai2,
                                              float* __restrict__ aj2) {
    const int lane = threadIdx.x & 63;
    const int n = blockIdx.x * 4 + (threadIdx.x >> 6);
    const float* r = xh2 + (size_t)n * C2;
    const float x0 = r[lane], x1 = r[lane + 64];
    float vi = x0 * atti[lane] + x1 * atti[lane + 64];
    float vj = x0 * attj[lane] + x1 * attj[lane + 64];
#pragma unroll
    for (int off = 32; off; off >>= 1) {
        vi += __shfl_xor(vi, off, 64);
        vj += __shfl_xor(vj, off, 64);
    }
    if (lane == 0) { ai2[n] = vi; aj2[n] = vj; }
}

// ---------------- Layer 2 aggregation (writes d_out) ----------------------
__global__ __launch_bounds__(256) void k_agg2(const float* __restrict__ xh2,
                                              const float* __restrict__ ai2v,
                                              const float* __restrict__ aj2v,
                                              const int* __restrict__ cursor,
                                              const int* __restrict__ csr,
                                              const float* __restrict__ bias,
                                              float* __restrict__ out) {
    const int lane = threadIdx.x & 63;
    const int i = blockIdx.x * 4 + (threadIdx.x >> 6);
    const float a_i = ai2v[i];
    float acc0 = 0.f, acc1 = 0.f, dsum = 0.f;
    const int deg = min(cursor[i], CAP);
    const int* rowp = csr + (size_t)i * CAP;
    for (int e = 0; e <= deg; ++e) {
        const int s = (e == deg) ? i : rowp[e];
        float aw = a_i + aj2v[s];
        aw = aw > 0.f ? aw : NEGS * aw;
        const float wv = __expf(aw);
        dsum += wv;
        const float* xr = xh2 + (size_t)s * C2;
        acc0 += wv * xr[lane];
        acc1 += wv * xr[lane + 64];
    }
    const float inv = 1.f / (dsum + 1e-16f);
    out[(size_t)i * C2 + lane]      = acc0 * inv + bias[lane];
    out[(size_t)i * C2 + lane + 64] = acc1 * inv + bias[lane + 64];
}

// ---------------- host glue ----------------------------------------------
extern "C" void kernel_launch(void* const* d_in, const int* in_sizes, int n_in,
                              void* d_out, int out_size, void* d_ws, size_t ws_size,
                              hipStream_t stream) {
    const float* x      = (const float*)d_in[0];
    const int*   ei     = (const int*)  d_in[1];
    const float* lin1_w = (const float*)d_in[2];
    const float* att1_i = (const float*)d_in[3];
    const float* att1_j = (const float*)d_in[4];
    const float* bias1  = (const float*)d_in[5];
    const float* lin2_w = (const float*)d_in[6];
    const float* att2_i = (const float*)d_in[7];
    const float* att2_j = (const float*)d_in[8];
    const float* bias2  = (const float*)d_in[9];
    float* out = (float*)d_out;

    char* wsb = (char*)d_ws;
    size_t off = 0;
    auto alloc = [&](size_t bytes) -> void* {
        void* p = wsb + off;
        off += (bytes + 255) & ~(size_t)255;
        return p;
    };
    int*   cursor = (int*)  alloc((size_t)NN * 4);
    int*   csr    = (int*)  alloc((size_t)NN * CAP * 4);
    float* xh1    = (float*)alloc((size_t)NN * HID * 4);
    float* ai1    = (float*)alloc((size_t)NN * NH1 * 4);
    float* aj1    = (float*)alloc((size_t)NN * NH1 * 4);
    float* h1     = (float*)alloc((size_t)NN * HID * 4);
    float* xh2    = (float*)alloc((size_t)NN * C2 * 4);
    float* ai2    = (float*)alloc((size_t)NN * 4);
    float* aj2    = (float*)alloc((size_t)NN * 4);
    if (off > ws_size) return;  // workspace too small: fail cleanly

    hipMemsetAsync(cursor, 0, (size_t)NN * 4, stream);
    k_scatter<<<NE / 256, 256, 0, stream>>>(ei, cursor, csr);
    k_gemm1<<<NN / 16, 256, 0, stream>>>(x, lin1_w, att1_i, att1_j, xh1, ai1, aj1);
    k_agg1<<<NN / 4, 256, 0, stream>>>(xh1, ai1, aj1, cursor, csr, bias1, h1);
    k_gemm2<<<NN / 16, 256, 0, stream>>>(h1, lin2_w, xh2);
    k_att2<<<NN / 4, 256, 0, stream>>>(xh2, att2_i, att2_j, ai2, aj2);
    k_agg2<<<NN / 4, 256, 0, stream>>>(xh2, ai2, aj2, cursor, csr, bias2, out);
}

// Round 2
// 371.808 us; speedup vs baseline: 1.1438x; 1.1438x over previous
//
#include <hip/hip_runtime.h>
#include <math.h>

#define NN   50000
#define NE   800000
#define FIN  128
#define HID  256     // H1*C1
#define NH1  8
#define C2   128
#define CAP  64
#define NEGS 0.2f

// bf16 pack/unpack (round-to-nearest-even)
__device__ inline unsigned short f2bf(float f) {
    union { float f; unsigned u; } v; v.f = f;
    unsigned u = v.u;
    u += 0x7fffu + ((u >> 16) & 1u);
    return (unsigned short)(u >> 16);
}
__device__ inline float bf2f(unsigned short h) {
    union { unsigned u; float f; } v; v.u = ((unsigned)h) << 16;
    return v.f;
}

// ---------------- CSR build: bucket scatter by destination ----------------
__global__ __launch_bounds__(256) void k_scatter(const int* __restrict__ ei,
                                                 int* __restrict__ cursor,
                                                 int* __restrict__ csr) {
    int e = blockIdx.x * 256 + threadIdx.x;
    if (e >= NE) return;
    int s = ei[e];
    int d = ei[NE + e];
    int slot = atomicAdd(&cursor[d], 1);
    if (slot < CAP) csr[d * CAP + slot] = s;
}

// ---------------- Layer 1 GEMM: xh1 = x @ W1^T (bf16 out), fused logits ---
// block: 256 threads. 16 rows x 256 cols per block. thread = 4 rows x 4 cols.
__global__ __launch_bounds__(256) void k_gemm1(const float* __restrict__ x,
                                               const float* __restrict__ w,
                                               const float* __restrict__ atti,
                                               const float* __restrict__ attj,
                                               unsigned short* __restrict__ xh,
                                               float* __restrict__ ai,
                                               float* __restrict__ aj) {
    __shared__ float xs[32][17];    // [kk][row], +1 pad kills transpose-store conflicts
    __shared__ float ws[32][256];   // [kk][col] = W[col][k0+kk]
    const int t  = threadIdx.x;
    const int tc = t & 63;          // col group (4 cols each)
    const int tr = t >> 6;          // row group == wave id (4 rows each)
    const int row0 = blockIdx.x * 16;

    float acc[4][4];
#pragma unroll
    for (int r = 0; r < 4; ++r)
#pragma unroll
        for (int c = 0; c < 4; ++c) acc[r][c] = 0.f;

    for (int k0 = 0; k0 < FIN; k0 += 32) {
        __syncthreads();
#pragma unroll
        for (int r = 0; r < 2; ++r) {
            int id = t + r * 256;
            int rr = id >> 5, kk = id & 31;
            xs[kk][rr] = x[(size_t)(row0 + rr) * FIN + k0 + kk];
        }
        {
            const float4* wp = (const float4*)(w + (size_t)t * FIN + k0);
#pragma unroll
            for (int q = 0; q < 8; ++q) {
                float4 v = wp[q];
                ws[q * 4 + 0][t] = v.x;
                ws[q * 4 + 1][t] = v.y;
                ws[q * 4 + 2][t] = v.z;
                ws[q * 4 + 3][t] = v.w;
            }
        }
        __syncthreads();
#pragma unroll
        for (int kk = 0; kk < 32; ++kk) {
            const float4 wv = ((const float4*)(&ws[kk][0]))[tc];
            const float x0 = xs[kk][tr * 4 + 0];
            const float x1 = xs[kk][tr * 4 + 1];
            const float x2 = xs[kk][tr * 4 + 2];
            const float x3 = xs[kk][tr * 4 + 3];
            acc[0][0] += x0 * wv.x; acc[0][1] += x0 * wv.y; acc[0][2] += x0 * wv.z; acc[0][3] += x0 * wv.w;
            acc[1][0] += x1 * wv.x; acc[1][1] += x1 * wv.y; acc[1][2] += x1 * wv.z; acc[1][3] += x1 * wv.w;
            acc[2][0] += x2 * wv.x; acc[2][1] += x2 * wv.y; acc[2][2] += x2 * wv.z; acc[2][3] += x2 * wv.w;
            acc[3][0] += x3 * wv.x; acc[3][1] += x3 * wv.y; acc[3][2] += x3 * wv.z; acc[3][3] += x3 * wv.w;
        }
    }

    // epilogue: write bf16 xh, reduce attention logits per (row, head)
    const float4 ai4 = ((const float4*)atti)[tc];
    const float4 aj4 = ((const float4*)attj)[tc];
    const int h = tc >> 3;          // 8 lanes (32 cols) per head
#pragma unroll
    for (int r = 0; r < 4; ++r) {
        const int row = row0 + tr * 4 + r;
        ushort4 pv;
        pv.x = f2bf(acc[r][0]); pv.y = f2bf(acc[r][1]);
        pv.z = f2bf(acc[r][2]); pv.w = f2bf(acc[r][3]);
        ((ushort4*)(xh + (size_t)row * HID))[tc] = pv;
        float vi = acc[r][0] * ai4.x + acc[r][1] * ai4.y + acc[r][2] * ai4.z + acc[r][3] * ai4.w;
        float vj = acc[r][0] * aj4.x + acc[r][1] * aj4.y + acc[r][2] * aj4.z + acc[r][3] * aj4.w;
#pragma unroll
        for (int off = 4; off; off >>= 1) {
            vi += __shfl_xor(vi, off, 8);
            vj += __shfl_xor(vj, off, 8);
        }
        if ((tc & 7) == 0) {
            ai[row * NH1 + h] = vi;
            aj[row * NH1 + h] = vj;
        }
    }
}

// ---------------- Layer 1 aggregation: one wave per destination node ------
// Each lane owns 4 consecutive cols (lane*4..lane*4+3), all in head lane>>3.
// Lane computes its own head's softmax weight -> no cross-lane shuffle in loop.
__global__ __launch_bounds__(256) void k_agg1(const unsigned short* __restrict__ xh,
                                              const float* __restrict__ ai,
                                              const float* __restrict__ aj,
                                              const int* __restrict__ cursor,
                                              const int* __restrict__ csr,
                                              const float* __restrict__ bias,
                                              float* __restrict__ hout) {
    const int lane = threadIdx.x & 63;
    const int i    = blockIdx.x * 4 + (threadIdx.x >> 6);
    const int myh  = lane >> 3;            // head owning this lane's 4 cols
    const float a_i = ai[i * NH1 + myh];

    float acc0 = 0.f, acc1 = 0.f, acc2 = 0.f, acc3 = 0.f, dsum = 0.f;
    const int deg = min(cursor[i], CAP);
    const int* rowp = csr + (size_t)i * CAP;

    for (int e = 0; e <= deg; ++e) {       // last iteration: self loop
        const int s = (e == deg) ? i : rowp[e];
        float aw = a_i + aj[s * NH1 + myh];
        aw = aw > 0.f ? aw : NEGS * aw;
        const float wv = __expf(aw);       // no max-subtraction: shift-invariant
        dsum += wv;
        const ushort4 v = ((const ushort4*)(xh + (size_t)s * HID))[lane];
        acc0 += wv * bf2f(v.x);
        acc1 += wv * bf2f(v.y);
        acc2 += wv * bf2f(v.z);
        acc3 += wv * bf2f(v.w);
    }
    const float inv = 1.f / (dsum + 1e-16f);
    const float4 b = ((const float4*)bias)[lane];
    float4 o;
    o.x = acc0 * inv + b.x;
    o.y = acc1 * inv + b.y;
    o.z = acc2 * inv + b.z;
    o.w = acc3 * inv + b.w;
    o.x = o.x > 0.f ? o.x : expm1f(o.x);   // ELU
    o.y = o.y > 0.f ? o.y : expm1f(o.y);
    o.z = o.z > 0.f ? o.z : expm1f(o.z);
    o.w = o.w > 0.f ? o.w : expm1f(o.w);
    ((float4*)(hout + (size_t)i * HID))[lane] = o;
}

// ---------------- Layer 2 GEMM: xh2 = h @ W2^T (bf16 out), fused logits ---
// block: 256 threads. 16 rows x 128 cols. thread = 2 rows x 4 cols.
__global__ __launch_bounds__(256) void k_gemm2(const float* __restrict__ hin,
                                               const float* __restrict__ w,
                                               const float* __restrict__ atti,
                                               const float* __restrict__ attj,
                                               unsigned short* __restrict__ xh2,
                                               float* __restrict__ ai2,
                                               float* __restrict__ aj2) {
    __shared__ float hs[32][17];
    __shared__ float ws[32][128];
    const int t  = threadIdx.x;
    const int tc = t & 31;    // col group (4 cols)
    const int tr = t >> 5;    // row group (2 rows)
    const int row0 = blockIdx.x * 16;

    float acc[2][4];
#pragma unroll
    for (int r = 0; r < 2; ++r)
#pragma unroll
        for (int c = 0; c < 4; ++c) acc[r][c] = 0.f;

    for (int k0 = 0; k0 < HID; k0 += 32) {
        __syncthreads();
#pragma unroll
        for (int r = 0; r < 2; ++r) {
            int id = t + r * 256;
            int rr = id >> 5, kk = id & 31;
            hs[kk][rr] = hin[(size_t)(row0 + rr) * HID + k0 + kk];
        }
        {
            const int c = t & 127;
            const int half = t >> 7;
            const float4* wp = (const float4*)(w + (size_t)c * HID + k0 + half * 16);
#pragma unroll
            for (int q = 0; q < 4; ++q) {
                float4 v = wp[q];
                ws[half * 16 + q * 4 + 0][c] = v.x;
                ws[half * 16 + q * 4 + 1][c] = v.y;
                ws[half * 16 + q * 4 + 2][c] = v.z;
                ws[half * 16 + q * 4 + 3][c] = v.w;
            }
        }
        __syncthreads();
#pragma unroll
        for (int kk = 0; kk < 32; ++kk) {
            const float4 wv = ((const float4*)(&ws[kk][0]))[tc];
            const float h0 = hs[kk][tr * 2 + 0];
            const float h1 = hs[kk][tr * 2 + 1];
            acc[0][0] += h0 * wv.x; acc[0][1] += h0 * wv.y; acc[0][2] += h0 * wv.z; acc[0][3] += h0 * wv.w;
            acc[1][0] += h1 * wv.x; acc[1][1] += h1 * wv.y; acc[1][2] += h1 * wv.z; acc[1][3] += h1 * wv.w;
        }
    }
    const float4 ai4 = ((const float4*)atti)[tc];
    const float4 aj4 = ((const float4*)attj)[tc];
#pragma unroll
    for (int r = 0; r < 2; ++r) {
        const int row = row0 + tr * 2 + r;
        ushort4 pv;
        pv.x = f2bf(acc[r][0]); pv.y = f2bf(acc[r][1]);
        pv.z = f2bf(acc[r][2]); pv.w = f2bf(acc[r][3]);
        ((ushort4*)(xh2 + (size_t)row * C2))[tc] = pv;
        float vi = acc[r][0] * ai4.x + acc[r][1] * ai4.y + acc[r][2] * ai4.z + acc[r][3] * ai4.w;
        float vj = acc[r][0] * aj4.x + acc[r][1] * aj4.y + acc[r][2] * aj4.z + acc[r][3] * aj4.w;
#pragma unroll
        for (int off = 16; off; off >>= 1) {
            vi += __shfl_xor(vi, off, 32);
            vj += __shfl_xor(vj, off, 32);
        }
        if (tc == 0) { ai2[row] = vi; aj2[row] = vj; }
    }
}

// ---------------- Layer 2 aggregation (writes d_out) ----------------------
// Single head: every lane computes the same weight; lane owns cols 2l, 2l+1.
__global__ __launch_bounds__(256) void k_agg2(const unsigned short* __restrict__ xh2,
                                              const float* __restrict__ ai2v,
                                              const float* __restrict__ aj2v,
                                              const int* __restrict__ cursor,
                                              const int* __restrict__ csr,
                                              const float* __restrict__ bias,
                                              float* __restrict__ out) {
    const int lane = threadIdx.x & 63;
    const int i = blockIdx.x * 4 + (threadIdx.x >> 6);
    const float a_i = ai2v[i];
    float acc0 = 0.f, acc1 = 0.f, dsum = 0.f;
    const int deg = min(cursor[i], CAP);
    const int* rowp = csr + (size_t)i * CAP;
    for (int e = 0; e <= deg; ++e) {
        const int s = (e == deg) ? i : rowp[e];
        float aw = a_i + aj2v[s];
        aw = aw > 0.f ? aw : NEGS * aw;
        const float wv = __expf(aw);
        dsum += wv;
        const ushort2 v = ((const ushort2*)(xh2 + (size_t)s * C2))[lane];
        acc0 += wv * bf2f(v.x);
        acc1 += wv * bf2f(v.y);
    }
    const float inv = 1.f / (dsum + 1e-16f);
    const float2 b = ((const float2*)bias)[lane];
    float2 o;
    o.x = acc0 * inv + b.x;
    o.y = acc1 * inv + b.y;
    ((float2*)(out + (size_t)i * C2))[lane] = o;
}

// ---------------- host glue ----------------------------------------------
extern "C" void kernel_launch(void* const* d_in, const int* in_sizes, int n_in,
                              void* d_out, int out_size, void* d_ws, size_t ws_size,
                              hipStream_t stream) {
    const float* x      = (const float*)d_in[0];
    const int*   ei     = (const int*)  d_in[1];
    const float* lin1_w = (const float*)d_in[2];
    const float* att1_i = (const float*)d_in[3];
    const float* att1_j = (const float*)d_in[4];
    const float* bias1  = (const float*)d_in[5];
    const float* lin2_w = (const float*)d_in[6];
    const float* att2_i = (const float*)d_in[7];
    const float* att2_j = (const float*)d_in[8];
    const float* bias2  = (const float*)d_in[9];
    float* out = (float*)d_out;

    char* wsb = (char*)d_ws;
    size_t off = 0;
    auto alloc = [&](size_t bytes) -> void* {
        void* p = wsb + off;
        off += (bytes + 255) & ~(size_t)255;
        return p;
    };
    int*            cursor = (int*)           alloc((size_t)NN * 4);
    int*            csr    = (int*)           alloc((size_t)NN * CAP * 4);
    unsigned short* xh1    = (unsigned short*)alloc((size_t)NN * HID * 2);
    float*          ai1    = (float*)         alloc((size_t)NN * NH1 * 4);
    float*          aj1    = (float*)         alloc((size_t)NN * NH1 * 4);
    float*          h1     = (float*)         alloc((size_t)NN * HID * 4);
    unsigned short* xh2    = (unsigned short*)alloc((size_t)NN * C2 * 2);
    float*          ai2    = (float*)         alloc((size_t)NN * 4);
    float*          aj2    = (float*)         alloc((size_t)NN * 4);
    if (off > ws_size) return;  // workspace too small: fail cleanly

    hipMemsetAsync(cursor, 0, (size_t)NN * 4, stream);
    k_scatter<<<NE / 256, 256, 0, stream>>>(ei, cursor, csr);
    k_gemm1<<<NN / 16, 256, 0, stream>>>(x, lin1_w, att1_i, att1_j, xh1, ai1, aj1);
    k_agg1<<<NN / 4, 256, 0, stream>>>(xh1, ai1, aj1, cursor, csr, bias1, h1);
    k_gemm2<<<NN / 16, 256, 0, stream>>>(h1, lin2_w, att2_i, att2_j, xh2, ai2, aj2);
    k_agg2<<<NN / 4, 256, 0, stream>>>(xh2, ai2, aj2, cursor, csr, bias2, out);
}

// Round 3
// 295.981 us; speedup vs baseline: 1.4369x; 1.2562x over previous
//
#include <hip/hip_runtime.h>
#include <math.h>

#define NN   50000
#define NE   800000
#define FIN  128
#define HID  256     // H1*C1
#define NH1  8
#define C2   128
#define CAP  64
#define NEGS 0.2f

// bf16 pack/unpack (round-to-nearest-even)
__device__ inline unsigned short f2bf(float f) {
    union { float f; unsigned u; } v; v.f = f;
    unsigned u = v.u;
    u += 0x7fffu + ((u >> 16) & 1u);
    return (unsigned short)(u >> 16);
}
__device__ inline float bf_lo(unsigned u) {
    union { unsigned u; float f; } v; v.u = u << 16;
    return v.f;
}
__device__ inline float bf_hi(unsigned u) {
    union { unsigned u; float f; } v; v.u = u & 0xffff0000u;
    return v.f;
}

// ---------------- CSR build: bucket scatter by destination ----------------
__global__ __launch_bounds__(256) void k_scatter(const int* __restrict__ ei,
                                                 int* __restrict__ cursor,
                                                 int* __restrict__ csr) {
    int e = blockIdx.x * 256 + threadIdx.x;
    if (e >= NE) return;
    int s = ei[e];
    int d = ei[NE + e];
    int slot = atomicAdd(&cursor[d], 1);
    if (slot < CAP) csr[d * CAP + slot] = s;
}

// ---------------- Layer 1 GEMM: xh1 = x @ W1^T (bf16 out), fused logits ---
__global__ __launch_bounds__(256) void k_gemm1(const float* __restrict__ x,
                                               const float* __restrict__ w,
                                               const float* __restrict__ atti,
                                               const float* __restrict__ attj,
                                               unsigned short* __restrict__ xh,
                                               float* __restrict__ ai,
                                               float* __restrict__ aj) {
    __shared__ float xs[32][17];
    __shared__ float ws[32][256];
    const int t  = threadIdx.x;
    const int tc = t & 63;
    const int tr = t >> 6;
    const int row0 = blockIdx.x * 16;

    float acc[4][4];
#pragma unroll
    for (int r = 0; r < 4; ++r)
#pragma unroll
        for (int c = 0; c < 4; ++c) acc[r][c] = 0.f;

    for (int k0 = 0; k0 < FIN; k0 += 32) {
        __syncthreads();
#pragma unroll
        for (int r = 0; r < 2; ++r) {
            int id = t + r * 256;
            int rr = id >> 5, kk = id & 31;
            xs[kk][rr] = x[(size_t)(row0 + rr) * FIN + k0 + kk];
        }
        {
            const float4* wp = (const float4*)(w + (size_t)t * FIN + k0);
#pragma unroll
            for (int q = 0; q < 8; ++q) {
                float4 v = wp[q];
                ws[q * 4 + 0][t] = v.x;
                ws[q * 4 + 1][t] = v.y;
                ws[q * 4 + 2][t] = v.z;
                ws[q * 4 + 3][t] = v.w;
            }
        }
        __syncthreads();
#pragma unroll
        for (int kk = 0; kk < 32; ++kk) {
            const float4 wv = ((const float4*)(&ws[kk][0]))[tc];
            const float x0 = xs[kk][tr * 4 + 0];
            const float x1 = xs[kk][tr * 4 + 1];
            const float x2 = xs[kk][tr * 4 + 2];
            const float x3 = xs[kk][tr * 4 + 3];
            acc[0][0] += x0 * wv.x; acc[0][1] += x0 * wv.y; acc[0][2] += x0 * wv.z; acc[0][3] += x0 * wv.w;
            acc[1][0] += x1 * wv.x; acc[1][1] += x1 * wv.y; acc[1][2] += x1 * wv.z; acc[1][3] += x1 * wv.w;
            acc[2][0] += x2 * wv.x; acc[2][1] += x2 * wv.y; acc[2][2] += x2 * wv.z; acc[2][3] += x2 * wv.w;
            acc[3][0] += x3 * wv.x; acc[3][1] += x3 * wv.y; acc[3][2] += x3 * wv.z; acc[3][3] += x3 * wv.w;
        }
    }

    const float4 ai4 = ((const float4*)atti)[tc];
    const float4 aj4 = ((const float4*)attj)[tc];
    const int h = tc >> 3;
#pragma unroll
    for (int r = 0; r < 4; ++r) {
        const int row = row0 + tr * 4 + r;
        ushort4 pv;
        pv.x = f2bf(acc[r][0]); pv.y = f2bf(acc[r][1]);
        pv.z = f2bf(acc[r][2]); pv.w = f2bf(acc[r][3]);
        ((ushort4*)(xh + (size_t)row * HID))[tc] = pv;
        float vi = acc[r][0] * ai4.x + acc[r][1] * ai4.y + acc[r][2] * ai4.z + acc[r][3] * ai4.w;
        float vj = acc[r][0] * aj4.x + acc[r][1] * aj4.y + acc[r][2] * aj4.z + acc[r][3] * aj4.w;
#pragma unroll
        for (int off = 4; off; off >>= 1) {
            vi += __shfl_xor(vi, off, 8);
            vj += __shfl_xor(vj, off, 8);
        }
        if ((tc & 7) == 0) {
            ai[row * NH1 + h] = vi;
            aj[row * NH1 + h] = vj;
        }
    }
}

// ---------------- Layer 1 aggregation ------------------------------------
// One wave per node. Lane covers 8 cols (16B bf16 load); 32 lanes cover a
// row, so a wave gathers 2 rows/instr (pair = lane>>5). Unroll x2 -> 4 rows
// in flight. CSR row prefetched into registers, s via shfl.
__global__ __launch_bounds__(256) void k_agg1(const unsigned short* __restrict__ xh,
                                              const float* __restrict__ ai,
                                              const float* __restrict__ aj,
                                              const int* __restrict__ cursor,
                                              const int* __restrict__ csr,
                                              const float* __restrict__ bias,
                                              float* __restrict__ hout) {
    const int lane = threadIdx.x & 63;
    const int i    = blockIdx.x * 4 + (threadIdx.x >> 6);
    const int sub  = lane & 31;        // col group: cols sub*8 .. sub*8+7
    const int pair = lane >> 5;        // which of 2 concurrent edges
    const int myh  = sub >> 2;         // head of these 8 cols
    const float a_i = ai[i * NH1 + myh];

    const int deg = min(cursor[i], CAP);
    const int nitems = deg + 1;        // + self loop
    const int* rowp = csr + (size_t)i * CAP;
    const int svals = (lane < deg) ? rowp[lane] : i;   // whole CSR row, 1 load

    float acc[8];
#pragma unroll
    for (int k = 0; k < 8; ++k) acc[k] = 0.f;
    float dsum = 0.f;

    for (int it = 0; it < nitems; it += 4) {
#pragma unroll
        for (int u = 0; u < 2; ++u) {
            const int e = it + u * 2 + pair;
            const int sh = __shfl(svals, e & 63, 64);
            const int s  = (e < deg) ? sh : i;
            float aw = a_i + aj[s * NH1 + myh];
            aw = aw > 0.f ? aw : NEGS * aw;
            const float wv = (e < nitems) ? __expf(aw) : 0.f;
            dsum += wv;
            const int4 raw = ((const int4*)(xh + (size_t)s * HID))[sub];
            acc[0] += wv * bf_lo((unsigned)raw.x);
            acc[1] += wv * bf_hi((unsigned)raw.x);
            acc[2] += wv * bf_lo((unsigned)raw.y);
            acc[3] += wv * bf_hi((unsigned)raw.y);
            acc[4] += wv * bf_lo((unsigned)raw.z);
            acc[5] += wv * bf_hi((unsigned)raw.z);
            acc[6] += wv * bf_lo((unsigned)raw.w);
            acc[7] += wv * bf_hi((unsigned)raw.w);
        }
    }
    // combine the two pair-halves (same cols, disjoint edge subsets)
    dsum += __shfl_xor(dsum, 32, 64);
#pragma unroll
    for (int k = 0; k < 8; ++k) acc[k] += __shfl_xor(acc[k], 32, 64);

    const float inv = 1.f / (dsum + 1e-16f);
    const float4 b = ((const float4*)bias)[sub * 2 + pair];
    float4 o;
    o.x = acc[pair * 4 + 0] * inv + b.x;
    o.y = acc[pair * 4 + 1] * inv + b.y;
    o.z = acc[pair * 4 + 2] * inv + b.z;
    o.w = acc[pair * 4 + 3] * inv + b.w;
    o.x = o.x > 0.f ? o.x : expm1f(o.x);   // ELU
    o.y = o.y > 0.f ? o.y : expm1f(o.y);
    o.z = o.z > 0.f ? o.z : expm1f(o.z);
    o.w = o.w > 0.f ? o.w : expm1f(o.w);
    ((float4*)(hout + (size_t)i * HID))[sub * 2 + pair] = o;
}

// ---------------- Layer 2 GEMM: xh2 = h @ W2^T (bf16 out), fused logits ---
__global__ __launch_bounds__(256) void k_gemm2(const float* __restrict__ hin,
                                               const float* __restrict__ w,
                                               const float* __restrict__ atti,
                                               const float* __restrict__ attj,
                                               unsigned short* __restrict__ xh2,
                                               float* __restrict__ ai2,
                                               float* __restrict__ aj2) {
    __shared__ float hs[32][17];
    __shared__ float ws[32][128];
    const int t  = threadIdx.x;
    const int tc = t & 31;
    const int tr = t >> 5;
    const int row0 = blockIdx.x * 16;

    float acc[2][4];
#pragma unroll
    for (int r = 0; r < 2; ++r)
#pragma unroll
        for (int c = 0; c < 4; ++c) acc[r][c] = 0.f;

    for (int k0 = 0; k0 < HID; k0 += 32) {
        __syncthreads();
#pragma unroll
        for (int r = 0; r < 2; ++r) {
            int id = t + r * 256;
            int rr = id >> 5, kk = id & 31;
            hs[kk][rr] = hin[(size_t)(row0 + rr) * HID + k0 + kk];
        }
        {
            const int c = t & 127;
            const int half = t >> 7;
            const float4* wp = (const float4*)(w + (size_t)c * HID + k0 + half * 16);
#pragma unroll
            for (int q = 0; q < 4; ++q) {
                float4 v = wp[q];
                ws[half * 16 + q * 4 + 0][c] = v.x;
                ws[half * 16 + q * 4 + 1][c] = v.y;
                ws[half * 16 + q * 4 + 2][c] = v.z;
                ws[half * 16 + q * 4 + 3][c] = v.w;
            }
        }
        __syncthreads();
#pragma unroll
        for (int kk = 0; kk < 32; ++kk) {
            const float4 wv = ((const float4*)(&ws[kk][0]))[tc];
            const float h0 = hs[kk][tr * 2 + 0];
            const float h1 = hs[kk][tr * 2 + 1];
            acc[0][0] += h0 * wv.x; acc[0][1] += h0 * wv.y; acc[0][2] += h0 * wv.z; acc[0][3] += h0 * wv.w;
            acc[1][0] += h1 * wv.x; acc[1][1] += h1 * wv.y; acc[1][2] += h1 * wv.z; acc[1][3] += h1 * wv.w;
        }
    }
    const float4 ai4 = ((const float4*)atti)[tc];
    const float4 aj4 = ((const float4*)attj)[tc];
#pragma unroll
    for (int r = 0; r < 2; ++r) {
        const int row = row0 + tr * 2 + r;
        ushort4 pv;
        pv.x = f2bf(acc[r][0]); pv.y = f2bf(acc[r][1]);
        pv.z = f2bf(acc[r][2]); pv.w = f2bf(acc[r][3]);
        ((ushort4*)(xh2 + (size_t)row * C2))[tc] = pv;
        float vi = acc[r][0] * ai4.x + acc[r][1] * ai4.y + acc[r][2] * ai4.z + acc[r][3] * ai4.w;
        float vj = acc[r][0] * aj4.x + acc[r][1] * aj4.y + acc[r][2] * aj4.z + acc[r][3] * aj4.w;
#pragma unroll
        for (int off = 16; off; off >>= 1) {
            vi += __shfl_xor(vi, off, 32);
            vj += __shfl_xor(vj, off, 32);
        }
        if (tc == 0) { ai2[row] = vi; aj2[row] = vj; }
    }
}

// ---------------- Layer 2 aggregation (writes d_out) ----------------------
// Lane covers 8 cols (16B); 16 lanes cover a row; quad = lane>>4 -> 4 edges
// per instr, unroll x2 -> 8 rows in flight. Single head.
__global__ __launch_bounds__(256) void k_agg2(const unsigned short* __restrict__ xh2,
                                              const float* __restrict__ ai2v,
                                              const float* __restrict__ aj2v,
                                              const int* __restrict__ cursor,
                                              const int* __restrict__ csr,
                                              const float* __restrict__ bias,
                                              float* __restrict__ out) {
    const int lane = threadIdx.x & 63;
    const int i    = blockIdx.x * 4 + (threadIdx.x >> 6);
    const int sub  = lane & 15;        // cols sub*8 .. sub*8+7
    const int quad = lane >> 4;        // which of 4 concurrent edges
    const float a_i = ai2v[i];

    const int deg = min(cursor[i], CAP);
    const int nitems = deg + 1;
    const int* rowp = csr + (size_t)i * CAP;
    const int svals = (lane < deg) ? rowp[lane] : i;

    float acc[8];
#pragma unroll
    for (int k = 0; k < 8; ++k) acc[k] = 0.f;
    float dsum = 0.f;

    for (int it = 0; it < nitems; it += 8) {
#pragma unroll
        for (int u = 0; u < 2; ++u) {
            const int e = it + u * 4 + quad;
            const int sh = __shfl(svals, e & 63, 64);
            const int s  = (e < deg) ? sh : i;
            float aw = a_i + aj2v[s];
            aw = aw > 0.f ? aw : NEGS * aw;
            const float wv = (e < nitems) ? __expf(aw) : 0.f;
            dsum += wv;
            const int4 raw = ((const int4*)(xh2 + (size_t)s * C2))[sub];
            acc[0] += wv * bf_lo((unsigned)raw.x);
            acc[1] += wv * bf_hi((unsigned)raw.x);
            acc[2] += wv * bf_lo((unsigned)raw.y);
            acc[3] += wv * bf_hi((unsigned)raw.y);
            acc[4] += wv * bf_lo((unsigned)raw.z);
            acc[5] += wv * bf_hi((unsigned)raw.z);
            acc[6] += wv * bf_lo((unsigned)raw.w);
            acc[7] += wv * bf_hi((unsigned)raw.w);
        }
    }
    dsum += __shfl_xor(dsum, 16, 64);
    dsum += __shfl_xor(dsum, 32, 64);
#pragma unroll
    for (int k = 0; k < 8; ++k) {
        acc[k] += __shfl_xor(acc[k], 16, 64);
        acc[k] += __shfl_xor(acc[k], 32, 64);
    }

    const float inv = 1.f / (dsum + 1e-16f);
    const float2 b = ((const float2*)bias)[sub * 4 + quad];
    float2 o;
    o.x = acc[quad * 2 + 0] * inv + b.x;
    o.y = acc[quad * 2 + 1] * inv + b.y;
    ((float2*)(out + (size_t)i * C2))[sub * 4 + quad] = o;
}

// ---------------- host glue ----------------------------------------------
extern "C" void kernel_launch(void* const* d_in, const int* in_sizes, int n_in,
                              void* d_out, int out_size, void* d_ws, size_t ws_size,
                              hipStream_t stream) {
    const float* x      = (const float*)d_in[0];
    const int*   ei     = (const int*)  d_in[1];
    const float* lin1_w = (const float*)d_in[2];
    const float* att1_i = (const float*)d_in[3];
    const float* att1_j = (const float*)d_in[4];
    const float* bias1  = (const float*)d_in[5];
    const float* lin2_w = (const float*)d_in[6];
    const float* att2_i = (const float*)d_in[7];
    const float* att2_j = (const float*)d_in[8];
    const float* bias2  = (const float*)d_in[9];
    float* out = (float*)d_out;

    char* wsb = (char*)d_ws;
    size_t off = 0;
    auto alloc = [&](size_t bytes) -> void* {
        void* p = wsb + off;
        off += (bytes + 255) & ~(size_t)255;
        return p;
    };
    int*            cursor = (int*)           alloc((size_t)NN * 4);
    int*            csr    = (int*)           alloc((size_t)NN * CAP * 4);
    unsigned short* xh1    = (unsigned short*)alloc((size_t)NN * HID * 2);
    float*          ai1    = (float*)         alloc((size_t)NN * NH1 * 4);
    float*          aj1    = (float*)         alloc((size_t)NN * NH1 * 4);
    float*          h1     = (float*)         alloc((size_t)NN * HID * 4);
    unsigned short* xh2    = (unsigned short*)alloc((size_t)NN * C2 * 2);
    float*          ai2    = (float*)         alloc((size_t)NN * 4);
    float*          aj2    = (float*)         alloc((size_t)NN * 4);
    if (off > ws_size) return;

    hipMemsetAsync(cursor, 0, (size_t)NN * 4, stream);
    k_scatter<<<NE / 256, 256, 0, stream>>>(ei, cursor, csr);
    k_gemm1<<<NN / 16, 256, 0, stream>>>(x, lin1_w, att1_i, att1_j, xh1, ai1, aj1);
    k_agg1<<<NN / 4, 256, 0, stream>>>(xh1, ai1, aj1, cursor, csr, bias1, h1);
    k_gemm2<<<NN / 16, 256, 0, stream>>>(h1, lin2_w, att2_i, att2_j, xh2, ai2, aj2);
    k_agg2<<<NN / 4, 256, 0, stream>>>(xh2, ai2, aj2, cursor, csr, bias2, out);
}

// Round 4
// 207.292 us; speedup vs baseline: 2.0516x; 1.4278x over previous
//
#include <hip/hip_runtime.h>
#include <math.h>

#define NN   50000
#define NE   800000
#define FIN  128
#define HID  256     // H1*C1
#define NH1  8
#define C2   128
#define CAP  64
#define NEGS 0.2f

typedef __attribute__((ext_vector_type(8))) short bf16x8;   // 8 bf16 = 4 VGPR
typedef __attribute__((ext_vector_type(4))) float f32x4;    // MFMA acc

// bf16 pack/unpack (round-to-nearest-even)
__device__ inline unsigned short f2bf(float f) {
    union { float f; unsigned u; } v; v.f = f;
    unsigned u = v.u;
    u += 0x7fffu + ((u >> 16) & 1u);
    return (unsigned short)(u >> 16);
}
__device__ inline float bf2f(unsigned short h) {
    union { unsigned u; float f; } v; v.u = ((unsigned)h) << 16;
    return v.f;
}
__device__ inline float bf_lo(unsigned u) {
    union { unsigned u; float f; } v; v.u = u << 16;
    return v.f;
}
__device__ inline float bf_hi(unsigned u) {
    union { unsigned u; float f; } v; v.u = u & 0xffff0000u;
    return v.f;
}

// ---------------- weight fp32 -> bf16 prep --------------------------------
__global__ __launch_bounds__(256) void k_prep(const float* __restrict__ w1,
                                              const float* __restrict__ w2,
                                              unsigned short* __restrict__ w1b,
                                              unsigned short* __restrict__ w2b) {
    int i = blockIdx.x * 256 + threadIdx.x;
    if (i < 32768) w1b[i] = f2bf(w1[i]);
    else if (i < 65536) w2b[i - 32768] = f2bf(w2[i - 32768]);
}

// ---------------- CSR build: bucket scatter by destination ----------------
__global__ __launch_bounds__(256) void k_scatter(const int* __restrict__ ei,
                                                 int* __restrict__ cursor,
                                                 int* __restrict__ csr) {
    int e = blockIdx.x * 256 + threadIdx.x;
    if (e >= NE) return;
    int s = ei[e];
    int d = ei[NE + e];
    int slot = atomicAdd(&cursor[d], 1);
    if (slot < CAP) csr[d * CAP + slot] = s;
}

// ---------------- Layer 1 GEMM (MFMA): xh1 = bf16( x @ W1^T ) -------------
// 512 threads = 8 waves, BM=128 (wave w -> 16 rows), N=256 (16 n-tiles).
// W1 (256x128) staged bf16 in LDS, 16B-chunk XOR swizzle (chunk ^= row&7).
__global__ __launch_bounds__(512, 4) void k_gemm1(const float* __restrict__ x,
                                                  const unsigned short* __restrict__ wb,
                                                  unsigned short* __restrict__ xh) {
    __shared__ unsigned short wl[HID * FIN];   // 256 rows x 128 k, 64 KB
    const int t = threadIdx.x;
    {   // stage: thread t -> row t>>1, chunks (t&1)*8 .. +7 (chunk = 8 bf16)
        const int row = t >> 1;
        const int c0  = (t & 1) * 8;
        const int4* src = (const int4*)(wb + row * FIN + c0 * 8);
#pragma unroll
        for (int j = 0; j < 8; ++j) {
            const int c = c0 + j;
            *(int4*)((char*)wl + row * 256 + ((c ^ (row & 7)) << 4)) = src[j];
        }
    }
    __syncthreads();

    const int w = t >> 6, l = t & 63, m = l & 15, q = l >> 4;
    const int arow = blockIdx.x * 128 + w * 16 + m;
    const int rowc = arow < NN ? arow : NN - 1;

    f32x4 acc[16];
#pragma unroll
    for (int nt = 0; nt < 16; ++nt)
#pragma unroll
        for (int b = 0; b < 4; ++b) acc[nt][b] = 0.f;

#pragma unroll
    for (int ks = 0; ks < 4; ++ks) {
        const int k0 = ks * 32 + q * 8;
        const float4 a0 = *(const float4*)(x + (size_t)rowc * FIN + k0);
        const float4 a1 = *(const float4*)(x + (size_t)rowc * FIN + k0 + 4);
        bf16x8 af;
        af[0] = (short)f2bf(a0.x); af[1] = (short)f2bf(a0.y);
        af[2] = (short)f2bf(a0.z); af[3] = (short)f2bf(a0.w);
        af[4] = (short)f2bf(a1.x); af[5] = (short)f2bf(a1.y);
        af[6] = (short)f2bf(a1.z); af[7] = (short)f2bf(a1.w);
        const int cb = ks * 4 + q;
#pragma unroll
        for (int nt = 0; nt < 16; ++nt) {
            const int n = nt * 16 + m;
            const bf16x8 bf = *(const bf16x8*)((const char*)wl + n * 256 + ((cb ^ (n & 7)) << 4));
            acc[nt] = __builtin_amdgcn_mfma_f32_16x16x32_bf16(af, bf, acc[nt], 0, 0, 0);
        }
    }

    // D: row = 4q+b (within tile), col = nt*16 + m
    const int orow = blockIdx.x * 128 + w * 16 + 4 * q;
#pragma unroll
    for (int b = 0; b < 4; ++b) {
        if (orow + b >= NN) break;
        unsigned short* dst = xh + (size_t)(orow + b) * HID + m;
#pragma unroll
        for (int nt = 0; nt < 16; ++nt) dst[nt * 16] = f2bf(acc[nt][b]);
    }
}

// ---------------- Layer 1 attention logits from bf16 xh -------------------
__global__ __launch_bounds__(256) void k_att1(const unsigned short* __restrict__ xh,
                                              const float* __restrict__ atti,
                                              const float* __restrict__ attj,
                                              float* __restrict__ ai,
                                              float* __restrict__ aj) {
    const int lane = threadIdx.x & 63;
    const int n = blockIdx.x * 4 + (threadIdx.x >> 6);
    const ushort4 v = ((const ushort4*)(xh + (size_t)n * HID))[lane];
    const float4 ci = ((const float4*)atti)[lane];   // att flat index == col
    const float4 cj = ((const float4*)attj)[lane];
    const float f0 = bf2f(v.x), f1 = bf2f(v.y), f2 = bf2f(v.z), f3 = bf2f(v.w);
    float vi = f0 * ci.x + f1 * ci.y + f2 * ci.z + f3 * ci.w;
    float vj = f0 * cj.x + f1 * cj.y + f2 * cj.z + f3 * cj.w;
#pragma unroll
    for (int off = 4; off; off >>= 1) {
        vi += __shfl_xor(vi, off, 8);
        vj += __shfl_xor(vj, off, 8);
    }
    if ((lane & 7) == 0) {
        ai[n * NH1 + (lane >> 3)] = vi;
        aj[n * NH1 + (lane >> 3)] = vj;
    }
}

// ---------------- Layer 1 aggregation (bf16 h1 out) -----------------------
__global__ __launch_bounds__(256) void k_agg1(const unsigned short* __restrict__ xh,
                                              const float* __restrict__ ai,
                                              const float* __restrict__ aj,
                                              const int* __restrict__ cursor,
                                              const int* __restrict__ csr,
                                              const float* __restrict__ bias,
                                              unsigned short* __restrict__ hout) {
    const int lane = threadIdx.x & 63;
    const int i    = blockIdx.x * 4 + (threadIdx.x >> 6);
    const int sub  = lane & 31;        // cols sub*8 .. sub*8+7
    const int pair = lane >> 5;        // which of 2 concurrent edges
    const int myh  = sub >> 2;
    const float a_i = ai[i * NH1 + myh];

    const int deg = min(cursor[i], CAP);
    const int nitems = deg + 1;
    const int* rowp = csr + (size_t)i * CAP;
    const int svals = (lane < deg) ? rowp[lane] : i;

    float acc[8];
#pragma unroll
    for (int k = 0; k < 8; ++k) acc[k] = 0.f;
    float dsum = 0.f;

    for (int it = 0; it < nitems; it += 4) {
#pragma unroll
        for (int u = 0; u < 2; ++u) {
            const int e = it + u * 2 + pair;
            const int sh = __shfl(svals, e & 63, 64);
            const int s  = (e < deg) ? sh : i;
            float aw = a_i + aj[s * NH1 + myh];
            aw = aw > 0.f ? aw : NEGS * aw;
            const float wv = (e < nitems) ? __expf(aw) : 0.f;
            dsum += wv;
            const int4 raw = ((const int4*)(xh + (size_t)s * HID))[sub];
            acc[0] += wv * bf_lo((unsigned)raw.x);
            acc[1] += wv * bf_hi((unsigned)raw.x);
            acc[2] += wv * bf_lo((unsigned)raw.y);
            acc[3] += wv * bf_hi((unsigned)raw.y);
            acc[4] += wv * bf_lo((unsigned)raw.z);
            acc[5] += wv * bf_hi((unsigned)raw.z);
            acc[6] += wv * bf_lo((unsigned)raw.w);
            acc[7] += wv * bf_hi((unsigned)raw.w);
        }
    }
    dsum += __shfl_xor(dsum, 32, 64);
#pragma unroll
    for (int k = 0; k < 8; ++k) acc[k] += __shfl_xor(acc[k], 32, 64);

    const float inv = 1.f / (dsum + 1e-16f);
    const float4 b = ((const float4*)bias)[sub * 2 + pair];
    float4 o;
    o.x = acc[pair * 4 + 0] * inv + b.x;
    o.y = acc[pair * 4 + 1] * inv + b.y;
    o.z = acc[pair * 4 + 2] * inv + b.z;
    o.w = acc[pair * 4 + 3] * inv + b.w;
    o.x = o.x > 0.f ? o.x : expm1f(o.x);   // ELU
    o.y = o.y > 0.f ? o.y : expm1f(o.y);
    o.z = o.z > 0.f ? o.z : expm1f(o.z);
    o.w = o.w > 0.f ? o.w : expm1f(o.w);
    ushort4 ov;
    ov.x = f2bf(o.x); ov.y = f2bf(o.y); ov.z = f2bf(o.z); ov.w = f2bf(o.w);
    ((ushort4*)(hout + (size_t)i * HID))[sub * 2 + pair] = ov;
}

// ---------------- Layer 2 GEMM (MFMA): xh2 = bf16( h1 @ W2^T ) ------------
// 512 threads, BM=128, N=128 (8 n-tiles), K=256 (8 k-steps). W2 in LDS.
__global__ __launch_bounds__(512, 4) void k_gemm2(const unsigned short* __restrict__ h1,
                                                  const unsigned short* __restrict__ wb,
                                                  unsigned short* __restrict__ xh2) {
    __shared__ unsigned short wl[C2 * HID];   // 128 rows x 256 k, 64 KB
    const int t = threadIdx.x;
    {   // stage: thread t -> row t>>2, chunks (t&3)*8 .. +7
        const int row = t >> 2;
        const int c0  = (t & 3) * 8;
        const int4* src = (const int4*)(wb + row * HID + c0 * 8);
#pragma unroll
        for (int j = 0; j < 8; ++j) {
            const int c = c0 + j;
            *(int4*)((char*)wl + row * 512 + ((c ^ (row & 7)) << 4)) = src[j];
        }
    }
    __syncthreads();

    const int w = t >> 6, l = t & 63, m = l & 15, q = l >> 4;
    const int arow = blockIdx.x * 128 + w * 16 + m;
    const int rowc = arow < NN ? arow : NN - 1;

    f32x4 acc[8];
#pragma unroll
    for (int nt = 0; nt < 8; ++nt)
#pragma unroll
        for (int b = 0; b < 4; ++b) acc[nt][b] = 0.f;

#pragma unroll
    for (int ks = 0; ks < 8; ++ks) {
        const int k0 = ks * 32 + q * 8;
        const bf16x8 af = *(const bf16x8*)(h1 + (size_t)rowc * HID + k0);
        const int cb = ks * 4 + q;
#pragma unroll
        for (int nt = 0; nt < 8; ++nt) {
            const int n = nt * 16 + m;
            const bf16x8 bf = *(const bf16x8*)((const char*)wl + n * 512 + ((cb ^ (n & 7)) << 4));
            acc[nt] = __builtin_amdgcn_mfma_f32_16x16x32_bf16(af, bf, acc[nt], 0, 0, 0);
        }
    }

    const int orow = blockIdx.x * 128 + w * 16 + 4 * q;
#pragma unroll
    for (int b = 0; b < 4; ++b) {
        if (orow + b >= NN) break;
        unsigned short* dst = xh2 + (size_t)(orow + b) * C2 + m;
#pragma unroll
        for (int nt = 0; nt < 8; ++nt) dst[nt * 16] = f2bf(acc[nt][b]);
    }
}

// ---------------- Layer 2 attention logits --------------------------------
__global__ __launch_bounds__(256) void k_att2(const unsigned short* __restrict__ xh2,
                                              const float* __restrict__ atti,
                                              const float* __restrict__ attj,
                                              float* __restrict__ ai2,
                                              float* __restrict__ aj2) {
    const int lane = threadIdx.x & 63;
    const int n = blockIdx.x * 4 + (threadIdx.x >> 6);
    const ushort2 v = ((const ushort2*)(xh2 + (size_t)n * C2))[lane];
    const float2 ci = ((const float2*)atti)[lane];
    const float2 cj = ((const float2*)attj)[lane];
    const float f0 = bf2f(v.x), f1 = bf2f(v.y);
    float vi = f0 * ci.x + f1 * ci.y;
    float vj = f0 * cj.x + f1 * cj.y;
#pragma unroll
    for (int off = 32; off; off >>= 1) {
        vi += __shfl_xor(vi, off, 64);
        vj += __shfl_xor(vj, off, 64);
    }
    if (lane == 0) { ai2[n] = vi; aj2[n] = vj; }
}

// ---------------- Layer 2 aggregation (writes d_out) ----------------------
__global__ __launch_bounds__(256) void k_agg2(const unsigned short* __restrict__ xh2,
                                              const float* __restrict__ ai2v,
                                              const float* __restrict__ aj2v,
                                              const int* __restrict__ cursor,
                                              const int* __restrict__ csr,
                                              const float* __restrict__ bias,
                                              float* __restrict__ out) {
    const int lane = threadIdx.x & 63;
    const int i    = blockIdx.x * 4 + (threadIdx.x >> 6);
    const int sub  = lane & 15;
    const int quad = lane >> 4;
    const float a_i = ai2v[i];

    const int deg = min(cursor[i], CAP);
    const int nitems = deg + 1;
    const int* rowp = csr + (size_t)i * CAP;
    const int svals = (lane < deg) ? rowp[lane] : i;

    float acc[8];
#pragma unroll
    for (int k = 0; k < 8; ++k) acc[k] = 0.f;
    float dsum = 0.f;

    for (int it = 0; it < nitems; it += 8) {
#pragma unroll
        for (int u = 0; u < 2; ++u) {
            const int e = it + u * 4 + quad;
            const int sh = __shfl(svals, e & 63, 64);
            const int s  = (e < deg) ? sh : i;
            float aw = a_i + aj2v[s];
            aw = aw > 0.f ? aw : NEGS * aw;
            const float wv = (e < nitems) ? __expf(aw) : 0.f;
            dsum += wv;
            const int4 raw = ((const int4*)(xh2 + (size_t)s * C2))[sub];
            acc[0] += wv * bf_lo((unsigned)raw.x);
            acc[1] += wv * bf_hi((unsigned)raw.x);
            acc[2] += wv * bf_lo((unsigned)raw.y);
            acc[3] += wv * bf_hi((unsigned)raw.y);
            acc[4] += wv * bf_lo((unsigned)raw.z);
            acc[5] += wv * bf_hi((unsigned)raw.z);
            acc[6] += wv * bf_lo((unsigned)raw.w);
            acc[7] += wv * bf_hi((unsigned)raw.w);
        }
    }
    dsum += __shfl_xor(dsum, 16, 64);
    dsum += __shfl_xor(dsum, 32, 64);
#pragma unroll
    for (int k = 0; k < 8; ++k) {
        acc[k] += __shfl_xor(acc[k], 16, 64);
        acc[k] += __shfl_xor(acc[k], 32, 64);
    }

    const float inv = 1.f / (dsum + 1e-16f);
    const float2 b = ((const float2*)bias)[sub * 4 + quad];
    float2 o;
    o.x = acc[quad * 2 + 0] * inv + b.x;
    o.y = acc[quad * 2 + 1] * inv + b.y;
    ((float2*)(out + (size_t)i * C2))[sub * 4 + quad] = o;
}

// ---------------- host glue ----------------------------------------------
extern "C" void kernel_launch(void* const* d_in, const int* in_sizes, int n_in,
                              void* d_out, int out_size, void* d_ws, size_t ws_size,
                              hipStream_t stream) {
    const float* x      = (const float*)d_in[0];
    const int*   ei     = (const int*)  d_in[1];
    const float* lin1_w = (const float*)d_in[2];
    const float* att1_i = (const float*)d_in[3];
    const float* att1_j = (const float*)d_in[4];
    const float* bias1  = (const float*)d_in[5];
    const float* lin2_w = (const float*)d_in[6];
    const float* att2_i = (const float*)d_in[7];
    const float* att2_j = (const float*)d_in[8];
    const float* bias2  = (const float*)d_in[9];
    float* out = (float*)d_out;

    char* wsb = (char*)d_ws;
    size_t off = 0;
    auto alloc = [&](size_t bytes) -> void* {
        void* p = wsb + off;
        off += (bytes + 255) & ~(size_t)255;
        return p;
    };
    int*            cursor = (int*)           alloc((size_t)NN * 4);
    int*            csr    = (int*)           alloc((size_t)NN * CAP * 4);
    unsigned short* w1b    = (unsigned short*)alloc((size_t)32768 * 2);
    unsigned short* w2b    = (unsigned short*)alloc((size_t)32768 * 2);
    unsigned short* xh1    = (unsigned short*)alloc((size_t)NN * HID * 2);
    float*          ai1    = (float*)         alloc((size_t)NN * NH1 * 4);
    float*          aj1    = (float*)         alloc((size_t)NN * NH1 * 4);
    unsigned short* h1     = (unsigned short*)alloc((size_t)NN * HID * 2);
    unsigned short* xh2    = (unsigned short*)alloc((size_t)NN * C2 * 2);
    float*          ai2    = (float*)         alloc((size_t)NN * 4);
    float*          aj2    = (float*)         alloc((size_t)NN * 4);
    if (off > ws_size) return;

    const int gm = (NN + 127) / 128;   // 391 blocks, tail guarded
    hipMemsetAsync(cursor, 0, (size_t)NN * 4, stream);
    k_prep<<<256, 256, 0, stream>>>(lin1_w, lin2_w, w1b, w2b);
    k_scatter<<<NE / 256, 256, 0, stream>>>(ei, cursor, csr);
    k_gemm1<<<gm, 512, 0, stream>>>(x, w1b, xh1);
    k_att1<<<NN / 4, 256, 0, stream>>>(xh1, att1_i, att1_j, ai1, aj1);
    k_agg1<<<NN / 4, 256, 0, stream>>>(xh1, ai1, aj1, cursor, csr, bias1, h1);
    k_gemm2<<<gm, 512, 0, stream>>>(h1, w2b, xh2);
    k_att2<<<NN / 4, 256, 0, stream>>>(xh2, att2_i, att2_j, ai2, aj2);
    k_agg2<<<NN / 4, 256, 0, stream>>>(xh2, ai2, aj2, cursor, csr, bias2, out);
}

// Round 5
// 190.347 us; speedup vs baseline: 2.2343x; 1.0890x over previous
//
#include <hip/hip_runtime.h>
#include <math.h>

#define NN   50000
#define NE   800000
#define FIN  128
#define HID  256     // H1*C1
#define NH1  8
#define C2   128
#define CAP  64
#define NEGS 0.2f

// extended weight geometry (attention logits fused as extra GEMM columns)
#define W1R  272     // 256 + 8 (att_i heads) + 8 (att_j heads)
#define W2R  144     // 128 + 1 (att_i) + 1 (att_j) + 14 zero pad

typedef __attribute__((ext_vector_type(8))) short bf16x8;   // 8 bf16 = 4 VGPR
typedef __attribute__((ext_vector_type(4))) float f32x4;    // MFMA acc

__device__ inline unsigned short f2bf(float f) {
    union { float f; unsigned u; } v; v.f = f;
    unsigned u = v.u;
    u += 0x7fffu + ((u >> 16) & 1u);
    return (unsigned short)(u >> 16);
}
__device__ inline float bf2f(unsigned short h) {
    union { unsigned u; float f; } v; v.u = ((unsigned)h) << 16;
    return v.f;
}
__device__ inline float bf_lo(unsigned u) {
    union { unsigned u; float f; } v; v.u = u << 16;
    return v.f;
}
__device__ inline float bf_hi(unsigned u) {
    union { unsigned u; float f; } v; v.u = u & 0xffff0000u;
    return v.f;
}

// ------ merged: CSR scatter + weight prep (bf16 convert + combined rows) ---
// blocks [0,3125): edge scatter. [3125,3381): w convert. [3381,3389): w~1.
// [3389,3391): w~2. [3391,3405): zero pad rows of w2ext.
__global__ __launch_bounds__(256) void k_scatter(const int* __restrict__ ei,
                                                 int* __restrict__ cursor,
                                                 int* __restrict__ csr,
                                                 const float* __restrict__ w1,
                                                 const float* __restrict__ w2,
                                                 const float* __restrict__ a1i,
                                                 const float* __restrict__ a1j,
                                                 const float* __restrict__ a2i,
                                                 const float* __restrict__ a2j,
                                                 unsigned short* __restrict__ w1e,
                                                 unsigned short* __restrict__ w2e) {
    const int B = blockIdx.x, t = threadIdx.x;
    if (B < 3125) {
        const int e = B * 256 + t;
        const int s = ei[e];
        const int d = ei[NE + e];
        const int slot = atomicAdd(&cursor[d], 1);
        if (slot < CAP) csr[d * CAP + slot] = s;
    } else if (B < 3381) {
        const int g = (B - 3125) * 256 + t;
        if (g < 32768) w1e[g] = f2bf(w1[g]);
        else w2e[g - 32768] = f2bf(w2[g - 32768]);
    } else if (B < 3389) {
        const int g = (B - 3381) * 256 + t;   // [0,2048): 16 rows x 128 k
        const int r = g >> 7, k = g & 127;
        const int h = r & 7;
        const float* att = (r < 8) ? a1i : a1j;
        float s = 0.f;
        for (int c = 0; c < 32; ++c)
            s += att[h * 32 + c] * w1[(h * 32 + c) * FIN + k];
        w1e[(256 + r) * FIN + k] = f2bf(s);
    } else if (B < 3391) {
        const int g = (B - 3389) * 256 + t;   // [0,512): 2 rows x 256 k
        const int r = g >> 8, k = g & 255;
        const float* att = (r == 0) ? a2i : a2j;
        float s = 0.f;
        for (int c = 0; c < C2; ++c)
            s += att[c] * w2[c * HID + k];
        w2e[(128 + r) * HID + k] = f2bf(s);
    } else {
        const int g = (B - 3391) * 256 + t;   // [0,3584): zero rows 130..143
        w2e[130 * HID + g] = 0;
    }
}

// ---------------- Layer 1 GEMM (MFMA): xh1 / ai1 / aj1 --------------------
// 512 threads = 8 waves, BM=128. 17 n-tiles (16 feature + 1 logit tile).
__global__ __launch_bounds__(512, 4) void k_gemm1(const float* __restrict__ x,
                                                  const unsigned short* __restrict__ wb,
                                                  unsigned short* __restrict__ xh,
                                                  float* __restrict__ ai,
                                                  float* __restrict__ aj) {
    __shared__ unsigned short wl[W1R * FIN];   // 272 rows x 128 k, 68 KB
    const int t = threadIdx.x;
    for (int idx = t; idx < W1R * 16; idx += 512) {   // 16-B chunks
        const int row = idx >> 4, c = idx & 15;
        *(int4*)((char*)wl + row * 256 + ((c ^ (row & 7)) << 4)) =
            *(const int4*)(wb + row * FIN + c * 8);
    }
    __syncthreads();

    const int w = t >> 6, l = t & 63, m = l & 15, q = l >> 4;
    const int arow = blockIdx.x * 128 + w * 16 + m;
    const int rowc = arow < NN ? arow : NN - 1;

    f32x4 acc[17];
#pragma unroll
    for (int nt = 0; nt < 17; ++nt)
#pragma unroll
        for (int b = 0; b < 4; ++b) acc[nt][b] = 0.f;

#pragma unroll
    for (int ks = 0; ks < 4; ++ks) {
        const int k0 = ks * 32 + q * 8;
        const float4 a0 = *(const float4*)(x + (size_t)rowc * FIN + k0);
        const float4 a1 = *(const float4*)(x + (size_t)rowc * FIN + k0 + 4);
        bf16x8 af;
        af[0] = (short)f2bf(a0.x); af[1] = (short)f2bf(a0.y);
        af[2] = (short)f2bf(a0.z); af[3] = (short)f2bf(a0.w);
        af[4] = (short)f2bf(a1.x); af[5] = (short)f2bf(a1.y);
        af[6] = (short)f2bf(a1.z); af[7] = (short)f2bf(a1.w);
        const int cb = ks * 4 + q;
#pragma unroll
        for (int nt = 0; nt < 17; ++nt) {
            const int n = nt * 16 + m;
            const bf16x8 bf = *(const bf16x8*)((const char*)wl + n * 256 + ((cb ^ (n & 7)) << 4));
            acc[nt] = __builtin_amdgcn_mfma_f32_16x16x32_bf16(af, bf, acc[nt], 0, 0, 0);
        }
    }

    // D: row = 4q+b (within wave tile), col = nt*16 + m
    const int orow = blockIdx.x * 128 + w * 16 + 4 * q;
#pragma unroll
    for (int b = 0; b < 4; ++b) {
        if (orow + b >= NN) break;
        unsigned short* dst = xh + (size_t)(orow + b) * HID + m;
#pragma unroll
        for (int nt = 0; nt < 16; ++nt) dst[nt * 16] = f2bf(acc[nt][b]);
        // logit tile: ext row 256+m -> m<8: ai head m, m>=8: aj head m-8
        if (m < 8) ai[(orow + b) * NH1 + m]       = acc[16][b];
        else       aj[(orow + b) * NH1 + (m - 8)] = acc[16][b];
    }
}

// ---------------- Layer 1 aggregation (bf16 h1 out) -----------------------
// 8 row-gathers in flight per wave (2 pair-split x 4 unroll).
__global__ __launch_bounds__(256) void k_agg1(const unsigned short* __restrict__ xh,
                                              const float* __restrict__ ai,
                                              const float* __restrict__ aj,
                                              const int* __restrict__ cursor,
                                              const int* __restrict__ csr,
                                              const float* __restrict__ bias,
                                              unsigned short* __restrict__ hout) {
    const int lane = threadIdx.x & 63;
    const int i    = blockIdx.x * 4 + (threadIdx.x >> 6);
    const int sub  = lane & 31;        // cols sub*8 .. sub*8+7
    const int pair = lane >> 5;        // which of 2 concurrent edges
    const int myh  = sub >> 2;
    const float a_i = ai[i * NH1 + myh];

    const int deg = min(cursor[i], CAP);
    const int nitems = deg + 1;
    const int* rowp = csr + (size_t)i * CAP;
    const int svals = (lane < deg) ? rowp[lane] : i;

    float acc[8];
#pragma unroll
    for (int k = 0; k < 8; ++k) acc[k] = 0.f;
    float dsum = 0.f;

    for (int it = 0; it < nitems; it += 8) {
#pragma unroll
        for (int u = 0; u < 4; ++u) {
            const int e = it + u * 2 + pair;
            const int sh = __shfl(svals, e & 63, 64);
            const int s  = (e < deg) ? sh : i;
            float aw = a_i + aj[s * NH1 + myh];
            aw = aw > 0.f ? aw : NEGS * aw;
            const float wv = (e < nitems) ? __expf(aw) : 0.f;
            dsum += wv;
            const int4 raw = ((const int4*)(xh + (size_t)s * HID))[sub];
            acc[0] += wv * bf_lo((unsigned)raw.x);
            acc[1] += wv * bf_hi((unsigned)raw.x);
            acc[2] += wv * bf_lo((unsigned)raw.y);
            acc[3] += wv * bf_hi((unsigned)raw.y);
            acc[4] += wv * bf_lo((unsigned)raw.z);
            acc[5] += wv * bf_hi((unsigned)raw.z);
            acc[6] += wv * bf_lo((unsigned)raw.w);
            acc[7] += wv * bf_hi((unsigned)raw.w);
        }
    }
    dsum += __shfl_xor(dsum, 32, 64);
#pragma unroll
    for (int k = 0; k < 8; ++k) acc[k] += __shfl_xor(acc[k], 32, 64);

    const float inv = 1.f / (dsum + 1e-16f);
    const float4 b = ((const float4*)bias)[sub * 2 + pair];
    float4 o;
    o.x = acc[pair * 4 + 0] * inv + b.x;
    o.y = acc[pair * 4 + 1] * inv + b.y;
    o.z = acc[pair * 4 + 2] * inv + b.z;
    o.w = acc[pair * 4 + 3] * inv + b.w;
    o.x = o.x > 0.f ? o.x : expm1f(o.x);   // ELU
    o.y = o.y > 0.f ? o.y : expm1f(o.y);
    o.z = o.z > 0.f ? o.z : expm1f(o.z);
    o.w = o.w > 0.f ? o.w : expm1f(o.w);
    ushort4 ov;
    ov.x = f2bf(o.x); ov.y = f2bf(o.y); ov.z = f2bf(o.z); ov.w = f2bf(o.w);
    ((ushort4*)(hout + (size_t)i * HID))[sub * 2 + pair] = ov;
}

// ---------------- Layer 2 GEMM (MFMA): xh2 / ai2 / aj2 --------------------
// 512 threads, BM=128, 9 n-tiles (8 feature + 1 logit tile), K=256.
__global__ __launch_bounds__(512, 4) void k_gemm2(const unsigned short* __restrict__ h1,
                                                  const unsigned short* __restrict__ wb,
                                                  unsigned short* __restrict__ xh2,
                                                  float* __restrict__ ai2,
                                                  float* __restrict__ aj2) {
    __shared__ unsigned short wl[W2R * HID];   // 144 rows x 256 k, 72 KB
    const int t = threadIdx.x;
    for (int idx = t; idx < W2R * 32; idx += 512) {   // 16-B chunks
        const int row = idx >> 5, c = idx & 31;
        *(int4*)((char*)wl + row * 512 + ((c ^ (row & 7)) << 4)) =
            *(const int4*)(wb + row * HID + c * 8);
    }
    __syncthreads();

    const int w = t >> 6, l = t & 63, m = l & 15, q = l >> 4;
    const int arow = blockIdx.x * 128 + w * 16 + m;
    const int rowc = arow < NN ? arow : NN - 1;

    f32x4 acc[9];
#pragma unroll
    for (int nt = 0; nt < 9; ++nt)
#pragma unroll
        for (int b = 0; b < 4; ++b) acc[nt][b] = 0.f;

#pragma unroll
    for (int ks = 0; ks < 8; ++ks) {
        const int k0 = ks * 32 + q * 8;
        const bf16x8 af = *(const bf16x8*)(h1 + (size_t)rowc * HID + k0);
        const int cb = ks * 4 + q;
#pragma unroll
        for (int nt = 0; nt < 9; ++nt) {
            const int n = nt * 16 + m;
            const bf16x8 bf = *(const bf16x8*)((const char*)wl + n * 512 + ((cb ^ (n & 7)) << 4));
            acc[nt] = __builtin_amdgcn_mfma_f32_16x16x32_bf16(af, bf, acc[nt], 0, 0, 0);
        }
    }

    const int orow = blockIdx.x * 128 + w * 16 + 4 * q;
#pragma unroll
    for (int b = 0; b < 4; ++b) {
        if (orow + b >= NN) break;
        unsigned short* dst = xh2 + (size_t)(orow + b) * C2 + m;
#pragma unroll
        for (int nt = 0; nt < 8; ++nt) dst[nt * 16] = f2bf(acc[nt][b]);
        if (m == 0) ai2[orow + b] = acc[8][b];
        if (m == 1) aj2[orow + b] = acc[8][b];
    }
}

// ---------------- Layer 2 aggregation (writes d_out) ----------------------
__global__ __launch_bounds__(256) void k_agg2(const unsigned short* __restrict__ xh2,
                                              const float* __restrict__ ai2v,
                                              const float* __restrict__ aj2v,
                                              const int* __restrict__ cursor,
                                              const int* __restrict__ csr,
                                              const float* __restrict__ bias,
                                              float* __restrict__ out) {
    const int lane = threadIdx.x & 63;
    const int i    = blockIdx.x * 4 + (threadIdx.x >> 6);
    const int sub  = lane & 15;
    const int quad = lane >> 4;
    const float a_i = ai2v[i];

    const int deg = min(cursor[i], CAP);
    const int nitems = deg + 1;
    const int* rowp = csr + (size_t)i * CAP;
    const int svals = (lane < deg) ? rowp[lane] : i;

    float acc[8];
#pragma unroll
    for (int k = 0; k < 8; ++k) acc[k] = 0.f;
    float dsum = 0.f;

    for (int it = 0; it < nitems; it += 8) {
#pragma unroll
        for (int u = 0; u < 2; ++u) {
            const int e = it + u * 4 + quad;
            const int sh = __shfl(svals, e & 63, 64);
            const int s  = (e < deg) ? sh : i;
            float aw = a_i + aj2v[s];
            aw = aw > 0.f ? aw : NEGS * aw;
            const float wv = (e < nitems) ? __expf(aw) : 0.f;
            dsum += wv;
            const int4 raw = ((const int4*)(xh2 + (size_t)s * C2))[sub];
            acc[0] += wv * bf_lo((unsigned)raw.x);
            acc[1] += wv * bf_hi((unsigned)raw.x);
            acc[2] += wv * bf_lo((unsigned)raw.y);
            acc[3] += wv * bf_hi((unsigned)raw.y);
            acc[4] += wv * bf_lo((unsigned)raw.z);
            acc[5] += wv * bf_hi((unsigned)raw.z);
            acc[6] += wv * bf_lo((unsigned)raw.w);
            acc[7] += wv * bf_hi((unsigned)raw.w);
        }
    }
    dsum += __shfl_xor(dsum, 16, 64);
    dsum += __shfl_xor(dsum, 32, 64);
#pragma unroll
    for (int k = 0; k < 8; ++k) {
        acc[k] += __shfl_xor(acc[k], 16, 64);
        acc[k] += __shfl_xor(acc[k], 32, 64);
    }

    const float inv = 1.f / (dsum + 1e-16f);
    const float2 b = ((const float2*)bias)[sub * 4 + quad];
    float2 o;
    o.x = acc[quad * 2 + 0] * inv + b.x;
    o.y = acc[quad * 2 + 1] * inv + b.y;
    ((float2*)(out + (size_t)i * C2))[sub * 4 + quad] = o;
}

// ---------------- host glue ----------------------------------------------
extern "C" void kernel_launch(void* const* d_in, const int* in_sizes, int n_in,
                              void* d_out, int out_size, void* d_ws, size_t ws_size,
                              hipStream_t stream) {
    const float* x      = (const float*)d_in[0];
    const int*   ei     = (const int*)  d_in[1];
    const float* lin1_w = (const float*)d_in[2];
    const float* att1_i = (const float*)d_in[3];
    const float* att1_j = (const float*)d_in[4];
    const float* bias1  = (const float*)d_in[5];
    const float* lin2_w = (const float*)d_in[6];
    const float* att2_i = (const float*)d_in[7];
    const float* att2_j = (const float*)d_in[8];
    const float* bias2  = (const float*)d_in[9];
    float* out = (float*)d_out;

    char* wsb = (char*)d_ws;
    size_t off = 0;
    auto alloc = [&](size_t bytes) -> void* {
        void* p = wsb + off;
        off += (bytes + 255) & ~(size_t)255;
        return p;
    };
    int*            cursor = (int*)           alloc((size_t)NN * 4);
    int*            csr    = (int*)           alloc((size_t)NN * CAP * 4);
    unsigned short* w1e    = (unsigned short*)alloc((size_t)W1R * FIN * 2);
    unsigned short* w2e    = (unsigned short*)alloc((size_t)W2R * HID * 2);
    unsigned short* xh1    = (unsigned short*)alloc((size_t)NN * HID * 2);
    float*          ai1    = (float*)         alloc((size_t)NN * NH1 * 4);
    float*          aj1    = (float*)         alloc((size_t)NN * NH1 * 4);
    unsigned short* h1     = (unsigned short*)alloc((size_t)NN * HID * 2);
    unsigned short* xh2    = (unsigned short*)alloc((size_t)NN * C2 * 2);
    float*          ai2    = (float*)         alloc((size_t)NN * 4);
    float*          aj2    = (float*)         alloc((size_t)NN * 4);
    if (off > ws_size) return;

    const int gm = (NN + 127) / 128;   // 391 blocks, tail guarded
    hipMemsetAsync(cursor, 0, (size_t)NN * 4, stream);
    k_scatter<<<3405, 256, 0, stream>>>(ei, cursor, csr, lin1_w, lin2_w,
                                        att1_i, att1_j, att2_i, att2_j, w1e, w2e);
    k_gemm1<<<gm, 512, 0, stream>>>(x, w1e, xh1, ai1, aj1);
    k_agg1<<<NN / 4, 256, 0, stream>>>(xh1, ai1, aj1, cursor, csr, bias1, h1);
    k_gemm2<<<gm, 512, 0, stream>>>(h1, w2e, xh2, ai2, aj2);
    k_agg2<<<NN / 4, 256, 0, stream>>>(xh2, ai2, aj2, cursor, csr, bias2, out);
}